// Round 2
// baseline (408.844 us; speedup 1.0000x reference)
//
#include <hip/hip_runtime.h>
#include <stdint.h>

#define NUM_HEADS 16
#define HEAD_DIM 64
#define D_MODEL 1024
#define SEQ 2048
#define BATCH 2

typedef unsigned short u16;
typedef __bf16 bf16x8 __attribute__((ext_vector_type(8)));
typedef float f32x4 __attribute__((ext_vector_type(4)));

__device__ __forceinline__ u16 f2bf(float f) {
    union { float f; uint32_t u; } v; v.f = f;
    uint32_t u = v.u;
    u += 0x7FFFu + ((u >> 16) & 1u);   // RNE
    return (u16)(u >> 16);
}
__device__ __forceinline__ float bf2f(u16 h) {
    union { uint32_t u; float f; } v; v.u = (uint32_t)h << 16; return v.f;
}

__device__ __forceinline__ bf16x8 ld8(const u16* p) {
    return *reinterpret_cast<const bf16x8*>(p);
}

__device__ __forceinline__ void gl_lds16(const void* g, void* l) {
    __builtin_amdgcn_global_load_lds(
        (const __attribute__((address_space(1))) void*)g,
        (__attribute__((address_space(3))) void*)l,
        16, 0, 0);
}

// ---------------- cast fp32 -> split bf16 (hi + lo planes) ----------------
__global__ __launch_bounds__(256) void k_cast_split(const float* __restrict__ in,
                                                    u16* __restrict__ hi,
                                                    u16* __restrict__ lo, int n4) {
    int i = blockIdx.x * 256 + threadIdx.x;
    if (i >= n4) return;
    float4 v = reinterpret_cast<const float4*>(in)[i];
    ushort4 h, l;
    h.x = f2bf(v.x); l.x = f2bf(v.x - bf2f(h.x));
    h.y = f2bf(v.y); l.y = f2bf(v.y - bf2f(h.y));
    h.z = f2bf(v.z); l.z = f2bf(v.z - bf2f(h.z));
    h.w = f2bf(v.w); l.w = f2bf(v.w - bf2f(h.w));
    reinterpret_cast<ushort4*>(hi)[i] = h;
    reinterpret_cast<ushort4*>(lo)[i] = l;
}

// ---------------- transpose + cast: W (K x N fp32) -> WT (N x K bf16), plain ----------------
__global__ __launch_bounds__(256) void k_transpose_bf16(const float* __restrict__ W,
                                                        u16* __restrict__ WT,
                                                        int K, int N) {
    __shared__ float tile[32][33];
    int bn = blockIdx.x * 32;
    int bk = blockIdx.y * 32;
    int tx = threadIdx.x & 31;
    int ty = threadIdx.x >> 5;
#pragma unroll
    for (int i = 0; i < 32; i += 8)
        tile[ty + i][tx] = W[(size_t)(bk + ty + i) * N + bn + tx];
    __syncthreads();
#pragma unroll
    for (int i = 0; i < 32; i += 8)
        WT[(size_t)(bn + ty + i) * K + bk + tx] = f2bf(tile[tx][ty + i]);
}

// ---------------- transpose + split cast: W -> WT hi/lo ----------------
__global__ __launch_bounds__(256) void k_transpose_split(const float* __restrict__ W,
                                                         u16* __restrict__ WTh,
                                                         u16* __restrict__ WTl,
                                                         int K, int N) {
    __shared__ float tile[32][33];
    int bn = blockIdx.x * 32;
    int bk = blockIdx.y * 32;
    int tx = threadIdx.x & 31;
    int ty = threadIdx.x >> 5;
#pragma unroll
    for (int i = 0; i < 32; i += 8)
        tile[ty + i][tx] = W[(size_t)(bk + ty + i) * N + bn + tx];
    __syncthreads();
#pragma unroll
    for (int i = 0; i < 32; i += 8) {
        float x = tile[tx][ty + i];
        u16 h = f2bf(x);
        u16 l = f2bf(x - bf2f(h));
        WTh[(size_t)(bn + ty + i) * K + bk + tx] = h;
        WTl[(size_t)(bn + ty + i) * K + bk + tx] = l;
    }
}

// ---------------- plain GEMM mainloop: C(128x128) = A * Bt^T ----------------
__device__ __forceinline__ void gemm_mainloop(const u16* __restrict__ A,
                                              const u16* __restrict__ Bt,
                                              u16* As, u16* Bs,
                                              int tileM, int tileN, int K,
                                              f32x4 acc[4][4]) {
    const int tid = threadIdx.x;
    const int lane = tid & 63;
    const int wv = tid >> 6;
    const int wm = wv >> 1, wn = wv & 1;
    const int quad = lane >> 4, l15 = lane & 15;

    const int c0 = tid, c1 = tid + 256;
    const u16* Ap0 = A + (size_t)(tileM + (c0 >> 2)) * K + (c0 & 3) * 8;
    const u16* Ap1 = A + (size_t)(tileM + (c1 >> 2)) * K + (c1 & 3) * 8;
    const u16* Bp0 = Bt + (size_t)(tileN + (c0 >> 2)) * K + (c0 & 3) * 8;
    const u16* Bp1 = Bt + (size_t)(tileN + (c1 >> 2)) * K + (c1 & 3) * 8;

    for (int k0 = 0; k0 < K; k0 += 32) {
        __syncthreads();
        gl_lds16(Ap0 + k0, &As[c0 * 8]);
        gl_lds16(Ap1 + k0, &As[c1 * 8]);
        gl_lds16(Bp0 + k0, &Bs[c0 * 8]);
        gl_lds16(Bp1 + k0, &Bs[c1 * 8]);
        __syncthreads();
        bf16x8 af[4], bfr[4];
#pragma unroll
        for (int mi = 0; mi < 4; ++mi)
            af[mi] = ld8(&As[(wm * 64 + mi * 16 + l15) * 32 + quad * 8]);
#pragma unroll
        for (int ni = 0; ni < 4; ++ni)
            bfr[ni] = ld8(&Bs[(wn * 64 + ni * 16 + l15) * 32 + quad * 8]);
#pragma unroll
        for (int mi = 0; mi < 4; ++mi)
#pragma unroll
            for (int ni = 0; ni < 4; ++ni)
                acc[mi][ni] = __builtin_amdgcn_mfma_f32_16x16x32_bf16(
                    af[mi], bfr[ni], acc[mi][ni], 0, 0, 0);
    }
}

// ---------------- split GEMM mainloop: acc += Ah*Bh + Ah*Bl + Al*Bh ----------------
__device__ __forceinline__ void gemm_mainloop_split(const u16* __restrict__ Ah,
                                                    const u16* __restrict__ Al,
                                                    const u16* __restrict__ Bh,
                                                    const u16* __restrict__ Bl,
                                                    u16* Ash, u16* Asl, u16* Bsh, u16* Bsl,
                                                    int tileM, int tileN, int K,
                                                    f32x4 acc[4][4]) {
    const int tid = threadIdx.x;
    const int lane = tid & 63;
    const int wv = tid >> 6;
    const int wm = wv >> 1, wn = wv & 1;
    const int quad = lane >> 4, l15 = lane & 15;

    const int c0 = tid, c1 = tid + 256;
    const size_t ao0 = (size_t)(tileM + (c0 >> 2)) * K + (c0 & 3) * 8;
    const size_t ao1 = (size_t)(tileM + (c1 >> 2)) * K + (c1 & 3) * 8;
    const size_t bo0 = (size_t)(tileN + (c0 >> 2)) * K + (c0 & 3) * 8;
    const size_t bo1 = (size_t)(tileN + (c1 >> 2)) * K + (c1 & 3) * 8;

    for (int k0 = 0; k0 < K; k0 += 32) {
        __syncthreads();
        gl_lds16(Ah + ao0 + k0, &Ash[c0 * 8]);
        gl_lds16(Ah + ao1 + k0, &Ash[c1 * 8]);
        gl_lds16(Al + ao0 + k0, &Asl[c0 * 8]);
        gl_lds16(Al + ao1 + k0, &Asl[c1 * 8]);
        gl_lds16(Bh + bo0 + k0, &Bsh[c0 * 8]);
        gl_lds16(Bh + bo1 + k0, &Bsh[c1 * 8]);
        gl_lds16(Bl + bo0 + k0, &Bsl[c0 * 8]);
        gl_lds16(Bl + bo1 + k0, &Bsl[c1 * 8]);
        __syncthreads();
        bf16x8 afh[4], afl[4], bfh[4], bfl[4];
#pragma unroll
        for (int mi = 0; mi < 4; ++mi) {
            afh[mi] = ld8(&Ash[(wm * 64 + mi * 16 + l15) * 32 + quad * 8]);
            afl[mi] = ld8(&Asl[(wm * 64 + mi * 16 + l15) * 32 + quad * 8]);
        }
#pragma unroll
        for (int ni = 0; ni < 4; ++ni) {
            bfh[ni] = ld8(&Bsh[(wn * 64 + ni * 16 + l15) * 32 + quad * 8]);
            bfl[ni] = ld8(&Bsl[(wn * 64 + ni * 16 + l15) * 32 + quad * 8]);
        }
#pragma unroll
        for (int mi = 0; mi < 4; ++mi)
#pragma unroll
            for (int ni = 0; ni < 4; ++ni) {
                acc[mi][ni] = __builtin_amdgcn_mfma_f32_16x16x32_bf16(
                    afh[mi], bfh[ni], acc[mi][ni], 0, 0, 0);
                acc[mi][ni] = __builtin_amdgcn_mfma_f32_16x16x32_bf16(
                    afh[mi], bfl[ni], acc[mi][ni], 0, 0, 0);
                acc[mi][ni] = __builtin_amdgcn_mfma_f32_16x16x32_bf16(
                    afl[mi], bfh[ni], acc[mi][ni], 0, 0, 0);
            }
    }
}

#define GEMM_IDS()                                                   \
    const int tileM = blockIdx.y * 128, tileN = blockIdx.x * 128;    \
    const int tid = threadIdx.x;                                     \
    const int lane = tid & 63;                                       \
    const int wv = tid >> 6;                                         \
    const int wm = wv >> 1, wn = wv & 1;                             \
    const int quad = lane >> 4, l15 = lane & 15;                     \
    (void)lane; (void)tid;

#define ACC_INIT()                                                   \
    f32x4 acc[4][4];                                                 \
    _Pragma("unroll") for (int i = 0; i < 4; ++i)                    \
        _Pragma("unroll") for (int j = 0; j < 4; ++j)                \
            acc[i][j] = (f32x4){0.f, 0.f, 0.f, 0.f};

// ---------------- Q projection (split) + LayerNorm + *8 -> Qh hi/lo ----------------
__global__ __launch_bounds__(256) void k_gemm_q(const u16* __restrict__ Ah,
                                                const u16* __restrict__ Al,
                                                const u16* __restrict__ Bh,
                                                const u16* __restrict__ Bl,
                                                const float* __restrict__ lng,
                                                const float* __restrict__ lnb,
                                                u16* __restrict__ Qh_h,
                                                u16* __restrict__ Qh_l) {
    __shared__ __align__(16) u16 Ash[128 * 32], Asl[128 * 32];
    __shared__ __align__(16) u16 Bsh[128 * 32], Bsl[128 * 32];
    GEMM_IDS(); ACC_INIT();
    gemm_mainloop_split(Ah, Al, Bh, Bl, Ash, Asl, Bsh, Bsl, tileM, tileN, D_MODEL, acc);

    float gv[4], bv[4];
#pragma unroll
    for (int ni = 0; ni < 4; ++ni) { gv[ni] = lng[ni * 16 + l15]; bv[ni] = lnb[ni * 16 + l15]; }

#pragma unroll
    for (int mi = 0; mi < 4; ++mi) {
#pragma unroll
        for (int r = 0; r < 4; ++r) {
            float sum = 0.f, sq = 0.f;
#pragma unroll
            for (int ni = 0; ni < 4; ++ni) { float x = acc[mi][ni][r]; sum += x; sq += x * x; }
#pragma unroll
            for (int off = 1; off < 16; off <<= 1) {
                sum += __shfl_xor(sum, off, 64);
                sq  += __shfl_xor(sq, off, 64);
            }
            float mu = sum * (1.f / 64.f);
            float var = sq * (1.f / 64.f) - mu * mu;
            float rs = rsqrtf(var + 1e-5f);
            int m = tileM + wm * 64 + mi * 16 + quad * 4 + r;
            int bb = m >> 11, n = m & (SEQ - 1);
#pragma unroll
            for (int ni = 0; ni < 4; ++ni) {
                int colg = tileN + wn * 64 + ni * 16 + l15;
                int h = colg >> 6;
                float y = ((acc[mi][ni][r] - mu) * rs * gv[ni] + bv[ni]) * 8.0f;
                size_t idx = (((size_t)bb * NUM_HEADS + h) * SEQ + n) * HEAD_DIM + (colg & 63);
                u16 yh = f2bf(y);
                Qh_h[idx] = yh;
                Qh_l[idx] = f2bf(y - bf2f(yh));
            }
        }
    }
}

// ---------------- KV projection: K-half split+LN -> Kh hi/lo; V-half plain -> VT ----------------
__global__ __launch_bounds__(256) void k_gemm_kv(const u16* __restrict__ Ah,
                                                 const u16* __restrict__ Al,
                                                 const u16* __restrict__ Bh,
                                                 const u16* __restrict__ Bl,
                                                 const float* __restrict__ lng,
                                                 const float* __restrict__ lnb,
                                                 u16* __restrict__ Kh_h,
                                                 u16* __restrict__ Kh_l,
                                                 u16* __restrict__ VT) {
    __shared__ __align__(16) u16 Ash[128 * 32], Asl[128 * 32];
    __shared__ __align__(16) u16 Bsh[128 * 32], Bsl[128 * 32];
    GEMM_IDS(); ACC_INIT();

    if (tileN < D_MODEL) {  // K columns: split precision + LayerNorm
        gemm_mainloop_split(Ah, Al, Bh, Bl, Ash, Asl, Bsh, Bsl, tileM, tileN, D_MODEL, acc);
        float gv[4], bv[4];
#pragma unroll
        for (int ni = 0; ni < 4; ++ni) { gv[ni] = lng[ni * 16 + l15]; bv[ni] = lnb[ni * 16 + l15]; }
#pragma unroll
        for (int mi = 0; mi < 4; ++mi) {
#pragma unroll
            for (int r = 0; r < 4; ++r) {
                float sum = 0.f, sq = 0.f;
#pragma unroll
                for (int ni = 0; ni < 4; ++ni) { float x = acc[mi][ni][r]; sum += x; sq += x * x; }
#pragma unroll
                for (int off = 1; off < 16; off <<= 1) {
                    sum += __shfl_xor(sum, off, 64);
                    sq  += __shfl_xor(sq, off, 64);
                }
                float mu = sum * (1.f / 64.f);
                float var = sq * (1.f / 64.f) - mu * mu;
                float rs = rsqrtf(var + 1e-5f);
                int m = tileM + wm * 64 + mi * 16 + quad * 4 + r;
                int bb = m >> 11, n = m & (SEQ - 1);
#pragma unroll
                for (int ni = 0; ni < 4; ++ni) {
                    int colg = tileN + wn * 64 + ni * 16 + l15;
                    int h = colg >> 6;
                    float y = (acc[mi][ni][r] - mu) * rs * gv[ni] + bv[ni];
                    size_t idx = (((size_t)bb * NUM_HEADS + h) * SEQ + n) * HEAD_DIM + (colg & 63);
                    u16 yh = f2bf(y);
                    Kh_h[idx] = yh;
                    Kh_l[idx] = f2bf(y - bf2f(yh));
                }
            }
        }
    } else {  // V columns: plain bf16, store transposed (d-major)
        gemm_mainloop(Ah, Bh, Ash, Bsh, tileM, tileN, D_MODEL, acc);
#pragma unroll
        for (int mi = 0; mi < 4; ++mi) {
            int m0 = tileM + wm * 64 + mi * 16 + quad * 4;
            int bb = m0 >> 11, n0 = m0 & (SEQ - 1);
#pragma unroll
            for (int ni = 0; ni < 4; ++ni) {
                int colg = tileN + wn * 64 + ni * 16 + l15 - D_MODEL;
                int h = colg >> 6, d = colg & 63;
                ushort4 o;
                o.x = f2bf(acc[mi][ni][0]);
                o.y = f2bf(acc[mi][ni][1]);
                o.z = f2bf(acc[mi][ni][2]);
                o.w = f2bf(acc[mi][ni][3]);
                *reinterpret_cast<ushort4*>(
                    &VT[(((size_t)bb * NUM_HEADS + h) * HEAD_DIM + d) * SEQ + n0]) = o;
            }
        }
    }
}

// ---------------- output projection + bias -> out fp32 (plain) ----------------
__global__ __launch_bounds__(256) void k_gemm_out(const u16* __restrict__ A,
                                                  const u16* __restrict__ Bt,
                                                  const float* __restrict__ bp,
                                                  float* __restrict__ out) {
    __shared__ __align__(16) u16 As[128 * 32];
    __shared__ __align__(16) u16 Bs[128 * 32];
    GEMM_IDS(); ACC_INIT();
    gemm_mainloop(A, Bt, As, Bs, tileM, tileN, D_MODEL, acc);

    float bpv[4];
#pragma unroll
    for (int ni = 0; ni < 4; ++ni) bpv[ni] = bp[tileN + wn * 64 + ni * 16 + l15];
#pragma unroll
    for (int mi = 0; mi < 4; ++mi) {
#pragma unroll
        for (int r = 0; r < 4; ++r) {
            int m = tileM + wm * 64 + mi * 16 + quad * 4 + r;
#pragma unroll
            for (int ni = 0; ni < 4; ++ni) {
                int colg = tileN + wn * 64 + ni * 16 + l15;
                out[(size_t)m * D_MODEL + colg] = acc[mi][ni][r] + bpv[ni];
            }
        }
    }
}

// ---------------- flash attention with split-bf16 Q,K (S = qh*kh + qh*kl + ql*kh) ----------------
__global__ __launch_bounds__(256) void k_attn(const u16* __restrict__ Qh_h,
                                              const u16* __restrict__ Qh_l,
                                              const u16* __restrict__ Kh_h,
                                              const u16* __restrict__ Kh_l,
                                              const u16* __restrict__ VT,
                                              u16* __restrict__ AO) {
    __shared__ __align__(16) u16 Ksh[64 * 72];
    __shared__ __align__(16) u16 Ksl[64 * 72];
    __shared__ __align__(16) u16 Vs[64 * 72];
    __shared__ __align__(16) u16 Ps[128 * 72];

    const int tid = threadIdx.x;
    const int lane = tid & 63;
    const int wv = tid >> 6;
    const int quad = lane >> 4, l15 = lane & 15;
    const int qt = blockIdx.x;   // 0..15
    const int bh = blockIdx.y;   // 0..31

    const size_t bh_off = (size_t)bh * SEQ * HEAD_DIM;
    const u16* Qbh_h = Qh_h + bh_off;
    const u16* Qbh_l = Qh_l + bh_off;
    const u16* Kbh_h = Kh_h + bh_off;
    const u16* Kbh_l = Kh_l + bh_off;
    const u16* Vbh = VT + (size_t)bh * HEAD_DIM * SEQ;

    bf16x8 qfh[2][2], qfl[2][2];
#pragma unroll
    for (int mi = 0; mi < 2; ++mi)
#pragma unroll
        for (int kt = 0; kt < 2; ++kt) {
            size_t off = (size_t)(qt * 128 + wv * 32 + mi * 16 + l15) * HEAD_DIM
                         + kt * 32 + quad * 8;
            qfh[mi][kt] = ld8(Qbh_h + off);
            qfl[mi][kt] = ld8(Qbh_l + off);
        }

    f32x4 acc_o[2][4];
    float m_i[2][4], l_i[2][4];
#pragma unroll
    for (int mi = 0; mi < 2; ++mi)
#pragma unroll
        for (int ni = 0; ni < 4; ++ni) acc_o[mi][ni] = (f32x4){0.f, 0.f, 0.f, 0.f};
#pragma unroll
    for (int mi = 0; mi < 2; ++mi)
#pragma unroll
        for (int r = 0; r < 4; ++r) { m_i[mi][r] = -3.0e38f; l_i[mi][r] = 0.f; }

    const uint4* Kgh = reinterpret_cast<const uint4*>(Kbh_h);
    const uint4* Kgl = reinterpret_cast<const uint4*>(Kbh_l);
    const uint4* Vg  = reinterpret_cast<const uint4*>(Vbh);

    for (int j = 0; j < SEQ / 64; ++j) {
        uint4 kregh[2], kregl[2], vreg[2];
#pragma unroll
        for (int i = 0; i < 2; ++i) {
            int c = tid + i * 256;
            kregh[i] = Kgh[(size_t)(j * 64 + (c >> 3)) * 8 + (c & 7)];
            kregl[i] = Kgl[(size_t)(j * 64 + (c >> 3)) * 8 + (c & 7)];
            vreg[i]  = Vg[(size_t)(c >> 3) * (SEQ / 8) + j * 8 + (c & 7)];
        }
        __syncthreads();
#pragma unroll
        for (int i = 0; i < 2; ++i) {
            int c = tid + i * 256;
            *reinterpret_cast<uint4*>(&Ksh[(c >> 3) * 72 + (c & 7) * 8]) = kregh[i];
            *reinterpret_cast<uint4*>(&Ksl[(c >> 3) * 72 + (c & 7) * 8]) = kregl[i];
            *reinterpret_cast<uint4*>(&Vs[(c >> 3) * 72 + (c & 7) * 8]) = vreg[i];
        }
        __syncthreads();

        // --- S = Q K^T with split precision ---
        f32x4 acc_s[2][4];
#pragma unroll
        for (int mi = 0; mi < 2; ++mi)
#pragma unroll
            for (int ni = 0; ni < 4; ++ni) acc_s[mi][ni] = (f32x4){0.f, 0.f, 0.f, 0.f};
#pragma unroll
        for (int kt = 0; kt < 2; ++kt) {
            bf16x8 kfh[4], kfl[4];
#pragma unroll
            for (int ni = 0; ni < 4; ++ni) {
                kfh[ni] = ld8(&Ksh[(ni * 16 + l15) * 72 + kt * 32 + quad * 8]);
                kfl[ni] = ld8(&Ksl[(ni * 16 + l15) * 72 + kt * 32 + quad * 8]);
            }
#pragma unroll
            for (int mi = 0; mi < 2; ++mi)
#pragma unroll
                for (int ni = 0; ni < 4; ++ni) {
                    acc_s[mi][ni] = __builtin_amdgcn_mfma_f32_16x16x32_bf16(
                        qfh[mi][kt], kfh[ni], acc_s[mi][ni], 0, 0, 0);
                    acc_s[mi][ni] = __builtin_amdgcn_mfma_f32_16x16x32_bf16(
                        qfh[mi][kt], kfl[ni], acc_s[mi][ni], 0, 0, 0);
                    acc_s[mi][ni] = __builtin_amdgcn_mfma_f32_16x16x32_bf16(
                        qfl[mi][kt], kfh[ni], acc_s[mi][ni], 0, 0, 0);
                }
        }

        // --- online softmax ---
#pragma unroll
        for (int mi = 0; mi < 2; ++mi) {
#pragma unroll
            for (int r = 0; r < 4; ++r) {
                float mx = -3.0e38f;
#pragma unroll
                for (int ni = 0; ni < 4; ++ni) mx = fmaxf(mx, acc_s[mi][ni][r]);
#pragma unroll
                for (int off = 1; off < 16; off <<= 1) mx = fmaxf(mx, __shfl_xor(mx, off, 64));
                float mold = m_i[mi][r];
                float mnew = fmaxf(mold, mx);
                float alpha = __expf(mold - mnew);
                float ps[4], sum = 0.f;
#pragma unroll
                for (int ni = 0; ni < 4; ++ni) {
                    ps[ni] = __expf(acc_s[mi][ni][r] - mnew);
                    sum += ps[ni];
                }
#pragma unroll
                for (int off = 1; off < 16; off <<= 1) sum += __shfl_xor(sum, off, 64);
                m_i[mi][r] = mnew;
                l_i[mi][r] = l_i[mi][r] * alpha + sum;
#pragma unroll
                for (int ni = 0; ni < 4; ++ni) acc_o[mi][ni][r] *= alpha;
                int row = wv * 32 + mi * 16 + quad * 4 + r;
#pragma unroll
                for (int ni = 0; ni < 4; ++ni)
                    Ps[row * 72 + ni * 16 + l15] = f2bf(ps[ni]);
            }
        }
        __syncthreads();

        // --- O += P V ---
#pragma unroll
        for (int kt = 0; kt < 2; ++kt) {
            bf16x8 pf[2], vf[4];
#pragma unroll
            for (int mi = 0; mi < 2; ++mi)
                pf[mi] = ld8(&Ps[(wv * 32 + mi * 16 + l15) * 72 + kt * 32 + quad * 8]);
#pragma unroll
            for (int ni = 0; ni < 4; ++ni)
                vf[ni] = ld8(&Vs[(ni * 16 + l15) * 72 + kt * 32 + quad * 8]);
#pragma unroll
            for (int mi = 0; mi < 2; ++mi)
#pragma unroll
                for (int ni = 0; ni < 4; ++ni)
                    acc_o[mi][ni] = __builtin_amdgcn_mfma_f32_16x16x32_bf16(
                        pf[mi], vf[ni], acc_o[mi][ni], 0, 0, 0);
        }
    }

    const int b = bh >> 4, h = bh & 15;
#pragma unroll
    for (int mi = 0; mi < 2; ++mi) {
#pragma unroll
        for (int r = 0; r < 4; ++r) {
            float inv = 1.0f / l_i[mi][r];
            int row = qt * 128 + wv * 32 + mi * 16 + quad * 4 + r;
#pragma unroll
            for (int ni = 0; ni < 4; ++ni)
                AO[((size_t)(b * SEQ + row)) * D_MODEL + h * 64 + ni * 16 + l15] =
                    f2bf(acc_o[mi][ni][r] * inv);
        }
    }
}

// ---------------- host ----------------
extern "C" void kernel_launch(void* const* d_in, const int* in_sizes, int n_in,
                              void* d_out, int out_size, void* d_ws, size_t ws_size,
                              hipStream_t stream) {
    const float* xq  = (const float*)d_in[0];
    const float* xc  = (const float*)d_in[1];
    const float* Wq  = (const float*)d_in[2];
    const float* Wkv = (const float*)d_in[3];
    const float* Wp  = (const float*)d_in[4];
    const float* bp  = (const float*)d_in[5];
    const float* lng = (const float*)d_in[6];
    const float* lnb = (const float*)d_in[7];
    float* out = (float*)d_out;

    char* ws = (char*)d_ws;
    const size_t MB = 1 << 20;
    u16* xq_h  = (u16*)(ws + 0 * MB);    // 8 MB
    u16* xq_l  = (u16*)(ws + 8 * MB);    // 8 MB
    u16* xc_h  = (u16*)(ws + 16 * MB);   // 8 MB
    u16* xc_l  = (u16*)(ws + 24 * MB);   // 8 MB
    u16* WqTh  = (u16*)(ws + 32 * MB);   // 2 MB
    u16* WqTl  = (u16*)(ws + 34 * MB);   // 2 MB
    u16* WkvTh = (u16*)(ws + 36 * MB);   // 4 MB
    u16* WkvTl = (u16*)(ws + 40 * MB);   // 4 MB
    u16* WpT   = (u16*)(ws + 44 * MB);   // 2 MB
    u16* Qh_h  = (u16*)(ws + 46 * MB);   // 8 MB
    u16* Qh_l  = (u16*)(ws + 54 * MB);   // 8 MB
    u16* Kh_h  = (u16*)(ws + 62 * MB);   // 8 MB
    u16* Kh_l  = (u16*)(ws + 70 * MB);   // 8 MB
    // aliases into regions that are dead by the time these are written:
    u16* VT = xq_l;   // written by k_gemm_kv (xq_l last read by k_gemm_q)
    u16* AO = xq_h;   // written by k_attn   (xq_h last read by k_gemm_q)

    k_cast_split<<<4096, 256, 0, stream>>>(xq, xq_h, xq_l, 1048576);
    k_cast_split<<<4096, 256, 0, stream>>>(xc, xc_h, xc_l, 1048576);
    k_transpose_split<<<dim3(32, 32), 256, 0, stream>>>(Wq, WqTh, WqTl, 1024, 1024);
    k_transpose_split<<<dim3(64, 32), 256, 0, stream>>>(Wkv, WkvTh, WkvTl, 1024, 2048);
    k_transpose_bf16<<<dim3(32, 32), 256, 0, stream>>>(Wp, WpT, 1024, 1024);

    k_gemm_q<<<dim3(8, 32), 256, 0, stream>>>(xq_h, xq_l, WqTh, WqTl, lng, lnb, Qh_h, Qh_l);
    k_gemm_kv<<<dim3(16, 32), 256, 0, stream>>>(xc_h, xc_l, WkvTh, WkvTl, lng, lnb,
                                                Kh_h, Kh_l, VT);
    k_attn<<<dim3(16, 32), 256, 0, stream>>>(Qh_h, Qh_l, Kh_h, Kh_l, VT, AO);
    k_gemm_out<<<dim3(8, 32), 256, 0, stream>>>(AO, WpT, bp, out);
}